// Round 11
// baseline (116.213 us; speedup 1.0000x reference)
//
#include <hip/hip_runtime.h>

#define EPS 1e-6f

typedef __attribute__((ext_vector_type(8))) short short8;   // 8 x bf16 bits
typedef __attribute__((ext_vector_type(16))) float f32x16;  // MFMA 32x32 acc

__device__ __forceinline__ float elu1(float x) {
    // elu(x) + 1  ==  x > 0 ? x + 1 : exp(x)
    return x > 0.f ? x + 1.f : __expf(x);
}

// fp32 -> bf16 bits, round-to-nearest-even
__device__ __forceinline__ short f2bf(float x) {
    unsigned u = __float_as_uint(x);
    return (short)((u + 0x7FFFu + ((u >> 16) & 1u)) >> 16);
}

// async global->LDS, 16B per lane; LDS dest = wave-uniform base + lane*16.
__device__ __forceinline__ void gl16(const float* g, float* l) {
    __builtin_amdgcn_global_load_lds(
        (const __attribute__((address_space(1))) unsigned int*)g,
        (__attribute__((address_space(3))) unsigned int*)l, 16, 0, 0);
}

#define VMCNT(n) asm volatile("s_waitcnt vmcnt(" #n ")" ::: "memory")
#define LGKMCNT0() asm volatile("s_waitcnt lgkmcnt(0)" ::: "memory")

// ---------------------------------------------------------------------------
// Phase 1 (R11 = R10 resubmit; R10 never ran, infra death during push):
// CONTIGUOUS global reads. One 1024-thr block (16 waves = the 16 heads of
// one n) per 64-row s-chunk. Per 2-row step, each wave issues ONE gl16 of a
// contiguous 1KB; collectively the 16 waves stage the step's 16KB (K rows
// q & q+8, V rows q & q+8 — complete 4KB rows, fully sequential in memory).
// 3-buffer LDS ring + counted VMCNT(1) + RAW s_barrier (NOT __syncthreads,
// which drains vmcnt(0)). ISSUE(st+2) placed right after the barrier (before
// the LDS reads) for extra load-lead; safe: the barrier orders iter st-1's
// consumed reads of SB[(st+2)%3] before the overwrite.
// Wave wv consumes its head's 256B slice per row; elu+mask+f2bf; MFMA fires
// every 8 steps with the R5-verified mapping (frag k = q+8*half; C/D:
// col=l&31, row=(r&3)+8*(r>>2)+4*half).
// ---------------------------------------------------------------------------
template<int NW>   // 16-row windows per block: NW=4 -> 64-row chunks
__global__ __launch_bounds__(1024, 1) void kv_partial_kernel(
    const float* __restrict__ keys, const float* __restrict__ values,
    const float* __restrict__ mask, float* __restrict__ pkv,
    float* __restrict__ pks)
{
    __shared__ float SB[3][2][2][1024];   // [ring][K/V][rsel][4KB row] = 48KB
    __shared__ float Mls[128];

    const int chunk = blockIdx.x, n = blockIdx.y;
    const int t = threadIdx.x;
    const int wv = t >> 6, l = t & 63;
    const int half = l >> 5, col = l & 31;
    const int s0 = chunk * (NW * 16);

    const float* kb = keys   + (size_t)(n * 4096 + s0) * 1024;
    const float* vb = values + (size_t)(n * 4096 + s0) * 1024;

    // staging role: arr (K/V), rsel (row q vs q+8), seg (1KB quarter of row)
    const int arr = wv & 1, rsel = (wv >> 1) & 1, seg = wv >> 2;
    const float* src = arr ? vb : kb;
    const int laneoff = seg * 256 + l * 4;      // floats within the row

    if (t < NW * 16) Mls[t] = mask[n * 4096 + s0 + t];

    f32x16 acc[2][2];
    #pragma unroll
    for (int a = 0; a < 2; ++a)
        #pragma unroll
        for (int b = 0; b < 2; ++b)
            #pragma unroll
            for (int r = 0; r < 16; ++r) acc[a][b][r] = 0.f;

    float ks0 = 0.f, ks1 = 0.f;
    short8 ka0, ka1, va0, va1;

#define ISSUE(ST)                                                          \
    { const int row_ = ((ST) >> 3) * 16 + ((ST) & 7) + 8 * rsel;           \
      gl16(src + (size_t)row_ * 1024 + laneoff,                            \
           &SB[(ST) % 3][arr][rsel][seg * 256]); }

    ISSUE(0);
    ISSUE(1);
    LGKMCNT0();                      // Mls ds_writes drained (all waves)
    __builtin_amdgcn_s_barrier();    // Mls visible block-wide

    #pragma unroll
    for (int w = 0; w < NW; ++w) {
        #pragma unroll
        for (int q = 0; q < 8; ++q) {
            const int st = w * 8 + q;
            VMCNT(1);                        // own gl16 for step st landed
            __builtin_amdgcn_s_barrier();    // everyone's st data in LDS
            if (st + 2 < NW * 8) ISSUE(st + 2);   // early: hide under compute
            const float msk = Mls[w * 16 + q + 8 * half];
            const float* Kp = &SB[st % 3][0][half][wv * 64];
            const float* Vp = &SB[st % 3][1][half][wv * 64];
            const float k0 = elu1(Kp[col]) * msk;
            const float k1 = elu1(Kp[col + 32]) * msk;
            ks0 += k0; ks1 += k1;
            ka0[q] = f2bf(k0); ka1[q] = f2bf(k1);
            va0[q] = f2bf(Vp[col]); va1[q] = f2bf(Vp[col + 32]);
            if (q == 7) {
                acc[0][0] = __builtin_amdgcn_mfma_f32_32x32x16_bf16(ka0, va0, acc[0][0], 0, 0, 0);
                acc[0][1] = __builtin_amdgcn_mfma_f32_32x32x16_bf16(ka0, va1, acc[0][1], 0, 0, 0);
                acc[1][0] = __builtin_amdgcn_mfma_f32_32x32x16_bf16(ka1, va0, acc[1][0], 0, 0, 0);
                acc[1][1] = __builtin_amdgcn_mfma_f32_32x32x16_bf16(ka1, va1, acc[1][1], 0, 0, 0);
            }
        }
    }
#undef ISSUE

    // ksum partial: halves cover complementary rows -> xor-32 totals
    ks0 += __shfl_xor(ks0, 32);
    ks1 += __shfl_xor(ks1, 32);
    const int nh = n * 16 + wv;
    pks[((size_t)chunk * 64 + nh) * 64 + l] = half ? ks1 : ks0;

    // dump partial in [d][m] order (verified C/D layout)
    float* pb = pkv + ((size_t)chunk * 64 + nh) * 4096;
    #pragma unroll
    for (int td = 0; td < 2; ++td)
        #pragma unroll
        for (int tm = 0; tm < 2; ++tm)
            #pragma unroll
            for (int r = 0; r < 16; ++r) {
                const int d = 32 * td + (r & 3) + 8 * (r >> 2) + 4 * half;
                pb[(size_t)d * 64 + 32 * tm + col] = acc[td][tm][r];
            }
}

// ---------------------------------------------------------------------------
// Reduce: kvt[nh][d][m] = sum_c pkv[c][nh][d][m];  ksum[nh][d] = sum_c pks.
// ---------------------------------------------------------------------------
__global__ __launch_bounds__(256) void kv_reduce_kernel(
    const float* __restrict__ pkv, const float* __restrict__ pks,
    float* __restrict__ kvt, float* __restrict__ ksum, int CH)
{
    const int nh = blockIdx.x;
    const int f4 = blockIdx.y * 256 + threadIdx.x;   // float4 slot 0..1023
    float4 s4 = make_float4(0.f, 0.f, 0.f, 0.f);
    #pragma unroll 4
    for (int c = 0; c < CH; ++c) {
        const float4 v = *(const float4*)(pkv + ((size_t)c * 64 + nh) * 4096 + f4 * 4);
        s4.x += v.x; s4.y += v.y; s4.z += v.z; s4.w += v.w;
    }
    *(float4*)(kvt + (size_t)nh * 4096 + f4 * 4) = s4;

    if (blockIdx.y == 0 && threadIdx.x < 64) {
        float s = 0.f;
        #pragma unroll 4
        for (int c = 0; c < CH; ++c)
            s += pks[((size_t)c * 64 + nh) * 64 + threadIdx.x];
        ksum[nh * 64 + threadIdx.x] = s;
    }
}

// ---------------------------------------------------------------------------
// Phase 2: out[n,l,h,m] = z_l * sum_d Q'[l,d] * KVT[d,m],
//          z_l = 1/(sum_d Q'[l,d]*Ksum[d] + EPS)   (R8/R9 version, ~BW-bound)
// ---------------------------------------------------------------------------
__global__ __launch_bounds__(256) void out_kernel(
    const float* __restrict__ queries, const float* __restrict__ kvt,
    const float* __restrict__ ksum, float* __restrict__ out)
{
    __shared__ float Qs[64][68];    // [l][d]
    __shared__ float KVs[64][68];   // [d][m]
    __shared__ float Ksm[64];

    const int nh = blockIdx.x;
    const int n = nh >> 4, h = nh & 15;
    const int t = threadIdx.x;
    const int l0 = blockIdx.y * 64;

    #pragma unroll
    for (int k = 0; k < 4; ++k) {
        const int idx = t + k * 256;
        *(float4*)&KVs[idx >> 4][(idx & 15) * 4] =
            *(const float4*)(kvt + (size_t)nh * 4096 + idx * 4);
    }
    if (t < 64) Ksm[t] = ksum[nh * 64 + t];

    #pragma unroll
    for (int k = 0; k < 4; ++k) {
        const int idx = t + k * 256;
        const int row = idx >> 4, seg = idx & 15;
        const size_t g = ((size_t)(n * 4096 + l0 + row) * 16 + h) * 64 + seg * 4;
        float4 q4 = *(const float4*)(queries + g);
        q4.x = elu1(q4.x);
        q4.y = elu1(q4.y);
        q4.z = elu1(q4.z);
        q4.w = elu1(q4.w);
        *(float4*)&Qs[row][seg * 4] = q4;
    }
    __syncthreads();

    const int mg = t & 7;          // m cols 4mg..+3 and 32+4mg..+3
    const int lg = t >> 3;         // 0..31; rows lg, lg+32

    float acc[2][8];
    float zacc[2] = {0.f, 0.f};
    #pragma unroll
    for (int i = 0; i < 2; ++i)
        #pragma unroll
        for (int j = 0; j < 8; ++j) acc[i][j] = 0.f;

    #pragma unroll 4
    for (int d0 = 0; d0 < 64; d0 += 4) {
        const float4 km4 = *(const float4*)&Ksm[d0];
        float4 q[2];
        q[0] = *(const float4*)&Qs[lg][d0];
        q[1] = *(const float4*)&Qs[lg + 32][d0];
        #pragma unroll
        for (int i = 0; i < 2; ++i)
            zacc[i] += q[i].x * km4.x + q[i].y * km4.y +
                       q[i].z * km4.z + q[i].w * km4.w;
        #pragma unroll
        for (int r = 0; r < 4; ++r) {
            const float4 kva = *(const float4*)&KVs[d0 + r][mg * 4];
            const float4 kvb = *(const float4*)&KVs[d0 + r][32 + mg * 4];
            #pragma unroll
            for (int i = 0; i < 2; ++i) {
                const float qc = ((const float*)&q[i])[r];
                acc[i][0] = fmaf(qc, kva.x, acc[i][0]);
                acc[i][1] = fmaf(qc, kva.y, acc[i][1]);
                acc[i][2] = fmaf(qc, kva.z, acc[i][2]);
                acc[i][3] = fmaf(qc, kva.w, acc[i][3]);
                acc[i][4] = fmaf(qc, kvb.x, acc[i][4]);
                acc[i][5] = fmaf(qc, kvb.y, acc[i][5]);
                acc[i][6] = fmaf(qc, kvb.z, acc[i][6]);
                acc[i][7] = fmaf(qc, kvb.w, acc[i][7]);
            }
        }
    }

    #pragma unroll
    for (int i = 0; i < 2; ++i) {
        const float z = 1.f / (zacc[i] + EPS);
        const int row = l0 + lg + 32 * i;
        const size_t g = ((size_t)(n * 4096 + row) * 16 + h) * 64;
        float4 o;
        o.x = acc[i][0] * z; o.y = acc[i][1] * z;
        o.z = acc[i][2] * z; o.w = acc[i][3] * z;
        *(float4*)(out + g + mg * 4) = o;
        o.x = acc[i][4] * z; o.y = acc[i][5] * z;
        o.z = acc[i][6] * z; o.w = acc[i][7] * z;
        *(float4*)(out + g + 32 + mg * 4) = o;
    }
}

extern "C" void kernel_launch(void* const* d_in, const int* in_sizes, int n_in,
                              void* d_out, int out_size, void* d_ws, size_t ws_size,
                              hipStream_t stream) {
    const float* queries = (const float*)d_in[0];
    const float* keys    = (const float*)d_in[1];
    const float* values  = (const float*)d_in[2];
    const float* mask    = (const float*)d_in[3];
    float* out = (float*)d_out;

    auto need = [](int CH) {
        return ((size_t)CH * 64 * 4096 + (size_t)CH * 64 * 64 +
                (size_t)64 * 4096 + 64 * 64) * sizeof(float);
    };
    // NW=4 -> 64-row chunks, CH=64 (69MB; ws proven >= this in R8);
    // fallback NW=8 -> 128-row chunks, CH=32 (35MB, proven in R5).
    const int CH = (need(64) <= ws_size) ? 64 : 32;

    float* pkv  = (float*)d_ws;                         // [CH][64][64][64] (d,m)
    float* pks  = pkv + (size_t)CH * 64 * 4096;         // [CH][64][64]
    float* kvt  = pks + (size_t)CH * 64 * 64;           // [64][64][64] (d,m)
    float* ksum = kvt + (size_t)64 * 4096;              // [64][64]

    if (CH == 64)
        kv_partial_kernel<4><<<dim3(64, 4), 1024, 0, stream>>>(keys, values, mask, pkv, pks);
    else
        kv_partial_kernel<8><<<dim3(32, 4), 1024, 0, stream>>>(keys, values, mask, pkv, pks);
    kv_reduce_kernel<<<dim3(64, 4), 256, 0, stream>>>(pkv, pks, kvt, ksum, CH);
    out_kernel<<<dim3(64, 64), 256, 0, stream>>>(queries, kvt, ksum, out);
}

// Round 12
// 88.982 us; speedup vs baseline: 1.3060x; 1.3060x over previous
//
#include <hip/hip_runtime.h>

#define EPS 1e-6f

typedef __attribute__((ext_vector_type(8))) short short8;   // 8 x bf16 bits
typedef __attribute__((ext_vector_type(16))) float f32x16;  // MFMA 32x32 acc

__device__ __forceinline__ float elu1(float x) {
    // elu(x) + 1  ==  x > 0 ? x + 1 : exp(x)
    return x > 0.f ? x + 1.f : __expf(x);
}

// fp32 -> bf16 bits, round-to-nearest-even
__device__ __forceinline__ short f2bf(float x) {
    unsigned u = __float_as_uint(x);
    return (short)((u + 0x7FFFu + ((u >> 16) & 1u)) >> 16);
}

// async global->LDS, 16B per lane; LDS dest = wave-uniform base + lane*16.
__device__ __forceinline__ void gl16(const float* g, float* l) {
    __builtin_amdgcn_global_load_lds(
        (const __attribute__((address_space(1))) unsigned int*)g,
        (__attribute__((address_space(3))) unsigned int*)l, 16, 0, 0);
}

#define VMCNT(n) asm volatile("s_waitcnt vmcnt(" #n ")" ::: "memory")
#define LGKMCNT0() asm volatile("s_waitcnt lgkmcnt(0)" ::: "memory")

// ---------------------------------------------------------------------------
// Phase 1 (R12 = R9 + deeper pipeline): one WAVE per (nh, chunk), wave-
// private LDS, no barriers, acc in AGPRs, gl16 staging. Changes vs R9
// (which sat at 60us, 85% vmcnt stall = latency x depth bound):
//   - masks preloaded once to LDS (vmcnt now counts ONLY gl16s: 8/step)
//   - 3-deep ring (24KB) with steady-state VMCNT(16): 16-24 gl16 in flight
//     (~2x R9's bytes in flight)
//   - STEPS compile-time so tail waits are exact literals (16/8/0)
// Fragment mapping (verified R5-R9):
//   A (K'^T): lane holds d=l&31 (+32*td), k-elems s=8*(l>>5)+j
//   B (V):    lane holds m=l&31 (+32*tm), same k
//   C/D:      col=l&31, row=(r&3)+8*(r>>2)+4*(l>>5)
// Ring-overwrite safety (same as R9): ISSUE(st+3) targets the slot computed
// at step st; all its ds_reads are drained by the compiler's lgkmcnt before
// the step's MFMAs, which precede the ISSUE in program order.
// ---------------------------------------------------------------------------
template<int STEPS>
__global__ __launch_bounds__(64) void kv_partial_kernel(
    const float* __restrict__ keys, const float* __restrict__ values,
    const float* __restrict__ mask, float* __restrict__ pkv,
    float* __restrict__ pks)
{
    __shared__ float Kls[3][16][64];     // 12 KB
    __shared__ float Vls[3][16][64];     // 12 KB
    __shared__ float Mls[STEPS * 16];

    const int nh = blockIdx.x;
    const int n = nh >> 4, h = nh & 15;
    const int chunk = blockIdx.y;
    const int l = threadIdx.x;
    const int half = l >> 5, col = l & 31;

    const int s0 = chunk * STEPS * 16;
    const float* kb = keys   + ((size_t)(n * 4096 + s0) * 16 + h) * 64;
    const float* vb = values + ((size_t)(n * 4096 + s0) * 16 + h) * 64;

    // per-lane global offset within a 4-row group: row l>>4, col (l&15)*4
    const size_t lanerow = (size_t)(l >> 4) * 1024 + (size_t)(l & 15) * 4;

    // mask preload: STEPS*16 floats, float4 per lane
    if (l < STEPS * 4)
        *(float4*)&Mls[l * 4] = *(const float4*)(mask + n * 4096 + s0 + l * 4);

    f32x16 acc[2][2];
    #pragma unroll
    for (int a = 0; a < 2; ++a)
        #pragma unroll
        for (int b = 0; b < 2; ++b)
            #pragma unroll
            for (int r = 0; r < 16; ++r) acc[a][b][r] = 0.f;

    float ks0 = 0.f, ks1 = 0.f;

#define ISSUE(ST)                                                         \
    { _Pragma("unroll")                                                   \
      for (int q = 0; q < 4; ++q) {                                       \
          const size_t go = (size_t)((ST) * 16 + 4 * q) * 1024 + lanerow; \
          gl16(kb + go, &Kls[(ST) % 3][4 * q][0]);                        \
          gl16(vb + go, &Vls[(ST) % 3][4 * q][0]);                        \
      } }

    ISSUE(0);
    ISSUE(1);
    ISSUE(2);
    LGKMCNT0();      // Mls ds_write drained before first Mls read

    #pragma unroll
    for (int st = 0; st < STEPS; ++st) {
        if (st + 2 < STEPS)      { VMCNT(16); }
        else if (st + 1 < STEPS) { VMCNT(8); }
        else                     { VMCNT(0); }
        const int p = st % 3;
        short8 ka0, ka1, va0, va1;
        #pragma unroll
        for (int j = 0; j < 8; ++j) {
            const int s = 8 * half + j;
            const float msk = Mls[st * 16 + s];
            const float k0 = elu1(Kls[p][s][col]) * msk;
            const float k1 = elu1(Kls[p][s][col + 32]) * msk;
            ks0 += k0; ks1 += k1;
            ka0[j] = f2bf(k0); ka1[j] = f2bf(k1);
            va0[j] = f2bf(Vls[p][s][col]);
            va1[j] = f2bf(Vls[p][s][col + 32]);
        }
        LGKMCNT0();
        acc[0][0] = __builtin_amdgcn_mfma_f32_32x32x16_bf16(ka0, va0, acc[0][0], 0, 0, 0);
        acc[0][1] = __builtin_amdgcn_mfma_f32_32x32x16_bf16(ka0, va1, acc[0][1], 0, 0, 0);
        acc[1][0] = __builtin_amdgcn_mfma_f32_32x32x16_bf16(ka1, va0, acc[1][0], 0, 0, 0);
        acc[1][1] = __builtin_amdgcn_mfma_f32_32x32x16_bf16(ka1, va1, acc[1][1], 0, 0, 0);
        if (st + 3 < STEPS) ISSUE(st + 3);
    }
#undef ISSUE

    // ksum partial: ks0 covers d=col (this half's rows), ks1 covers d=col+32
    ks0 += __shfl_xor(ks0, 32);
    ks1 += __shfl_xor(ks1, 32);
    pks[((size_t)chunk * 64 + nh) * 64 + l] = half ? ks1 : ks0;

    // dump partial, already in [d][m] order; each store = 2x128B segments
    float* pb = pkv + ((size_t)chunk * 64 + nh) * 4096;
    #pragma unroll
    for (int td = 0; td < 2; ++td)
        #pragma unroll
        for (int tm = 0; tm < 2; ++tm)
            #pragma unroll
            for (int r = 0; r < 16; ++r) {
                const int d = 32 * td + (r & 3) + 8 * (r >> 2) + 4 * half;
                pb[(size_t)d * 64 + 32 * tm + col] = acc[td][tm][r];
            }
}

// ---------------------------------------------------------------------------
// Reduce: kvt[nh][d][m] = sum_c pkv[c][nh][d][m];  ksum[nh][d] = sum_c pks.
// ---------------------------------------------------------------------------
__global__ __launch_bounds__(256) void kv_reduce_kernel(
    const float* __restrict__ pkv, const float* __restrict__ pks,
    float* __restrict__ kvt, float* __restrict__ ksum, int CH)
{
    const int nh = blockIdx.x;
    const int f4 = blockIdx.y * 256 + threadIdx.x;   // float4 slot 0..1023
    float4 s4 = make_float4(0.f, 0.f, 0.f, 0.f);
    #pragma unroll 4
    for (int c = 0; c < CH; ++c) {
        const float4 v = *(const float4*)(pkv + ((size_t)c * 64 + nh) * 4096 + f4 * 4);
        s4.x += v.x; s4.y += v.y; s4.z += v.z; s4.w += v.w;
    }
    *(float4*)(kvt + (size_t)nh * 4096 + f4 * 4) = s4;

    if (blockIdx.y == 0 && threadIdx.x < 64) {
        float s = 0.f;
        #pragma unroll 4
        for (int c = 0; c < CH; ++c)
            s += pks[((size_t)c * 64 + nh) * 64 + threadIdx.x];
        ksum[nh * 64 + threadIdx.x] = s;
    }
}

// ---------------------------------------------------------------------------
// Phase 2: out[n,l,h,m] = z_l * sum_d Q'[l,d] * KVT[d,m],
//          z_l = 1/(sum_d Q'[l,d]*Ksum[d] + EPS)   (R8/R9 version, ~BW-bound)
// ---------------------------------------------------------------------------
__global__ __launch_bounds__(256) void out_kernel(
    const float* __restrict__ queries, const float* __restrict__ kvt,
    const float* __restrict__ ksum, float* __restrict__ out)
{
    __shared__ float Qs[64][68];    // [l][d]
    __shared__ float KVs[64][68];   // [d][m]
    __shared__ float Ksm[64];

    const int nh = blockIdx.x;
    const int n = nh >> 4, h = nh & 15;
    const int t = threadIdx.x;
    const int l0 = blockIdx.y * 64;

    #pragma unroll
    for (int k = 0; k < 4; ++k) {
        const int idx = t + k * 256;
        *(float4*)&KVs[idx >> 4][(idx & 15) * 4] =
            *(const float4*)(kvt + (size_t)nh * 4096 + idx * 4);
    }
    if (t < 64) Ksm[t] = ksum[nh * 64 + t];

    #pragma unroll
    for (int k = 0; k < 4; ++k) {
        const int idx = t + k * 256;
        const int row = idx >> 4, seg = idx & 15;
        const size_t g = ((size_t)(n * 4096 + l0 + row) * 16 + h) * 64 + seg * 4;
        float4 q4 = *(const float4*)(queries + g);
        q4.x = elu1(q4.x);
        q4.y = elu1(q4.y);
        q4.z = elu1(q4.z);
        q4.w = elu1(q4.w);
        *(float4*)&Qs[row][seg * 4] = q4;
    }
    __syncthreads();

    const int mg = t & 7;          // m cols 4mg..+3 and 32+4mg..+3
    const int lg = t >> 3;         // 0..31; rows lg, lg+32

    float acc[2][8];
    float zacc[2] = {0.f, 0.f};
    #pragma unroll
    for (int i = 0; i < 2; ++i)
        #pragma unroll
        for (int j = 0; j < 8; ++j) acc[i][j] = 0.f;

    #pragma unroll 4
    for (int d0 = 0; d0 < 64; d0 += 4) {
        const float4 km4 = *(const float4*)&Ksm[d0];
        float4 q[2];
        q[0] = *(const float4*)&Qs[lg][d0];
        q[1] = *(const float4*)&Qs[lg + 32][d0];
        #pragma unroll
        for (int i = 0; i < 2; ++i)
            zacc[i] += q[i].x * km4.x + q[i].y * km4.y +
                       q[i].z * km4.z + q[i].w * km4.w;
        #pragma unroll
        for (int r = 0; r < 4; ++r) {
            const float4 kva = *(const float4*)&KVs[d0 + r][mg * 4];
            const float4 kvb = *(const float4*)&KVs[d0 + r][32 + mg * 4];
            #pragma unroll
            for (int i = 0; i < 2; ++i) {
                const float qc = ((const float*)&q[i])[r];
                acc[i][0] = fmaf(qc, kva.x, acc[i][0]);
                acc[i][1] = fmaf(qc, kva.y, acc[i][1]);
                acc[i][2] = fmaf(qc, kva.z, acc[i][2]);
                acc[i][3] = fmaf(qc, kva.w, acc[i][3]);
                acc[i][4] = fmaf(qc, kvb.x, acc[i][4]);
                acc[i][5] = fmaf(qc, kvb.y, acc[i][5]);
                acc[i][6] = fmaf(qc, kvb.z, acc[i][6]);
                acc[i][7] = fmaf(qc, kvb.w, acc[i][7]);
            }
        }
    }

    #pragma unroll
    for (int i = 0; i < 2; ++i) {
        const float z = 1.f / (zacc[i] + EPS);
        const int row = l0 + lg + 32 * i;
        const size_t g = ((size_t)(n * 4096 + row) * 16 + h) * 64;
        float4 o;
        o.x = acc[i][0] * z; o.y = acc[i][1] * z;
        o.z = acc[i][2] * z; o.w = acc[i][3] * z;
        *(float4*)(out + g + mg * 4) = o;
        o.x = acc[i][4] * z; o.y = acc[i][5] * z;
        o.z = acc[i][6] * z; o.w = acc[i][7] * z;
        *(float4*)(out + g + 32 + mg * 4) = o;
    }
}

extern "C" void kernel_launch(void* const* d_in, const int* in_sizes, int n_in,
                              void* d_out, int out_size, void* d_ws, size_t ws_size,
                              hipStream_t stream) {
    const float* queries = (const float*)d_in[0];
    const float* keys    = (const float*)d_in[1];
    const float* values  = (const float*)d_in[2];
    const float* mask    = (const float*)d_in[3];
    float* out = (float*)d_out;

    auto need = [](int CH) {
        return ((size_t)CH * 64 * 4096 + (size_t)CH * 64 * 64 +
                (size_t)64 * 4096 + 64 * 64) * sizeof(float);
    };
    // CH=32 (35MB, proven fits in R5/R9); fallback CH=16 (18MB, proven R1).
    const int CH = (need(32) <= ws_size) ? 32 : 16;

    float* pkv  = (float*)d_ws;                         // [CH][64][64][64] (d,m)
    float* pks  = pkv + (size_t)CH * 64 * 4096;         // [CH][64][64]
    float* kvt  = pks + (size_t)CH * 64 * 64;           // [64][64][64] (d,m)
    float* ksum = kvt + (size_t)64 * 4096;              // [64][64]

    if (CH == 32)
        kv_partial_kernel<8><<<dim3(64, 32), 64, 0, stream>>>(keys, values, mask, pkv, pks);
    else
        kv_partial_kernel<16><<<dim3(64, 16), 64, 0, stream>>>(keys, values, mask, pkv, pks);
    kv_reduce_kernel<<<dim3(64, 4), 256, 0, stream>>>(pkv, pks, kvt, ksum, CH);
    out_kernel<<<dim3(64, 64), 256, 0, stream>>>(queries, kvt, ksum, out);
}

// Round 13
// 79.755 us; speedup vs baseline: 1.4571x; 1.1157x over previous
//
#include <hip/hip_runtime.h>

#define EPS 1e-6f

typedef __attribute__((ext_vector_type(8))) short short8;   // 8 x bf16 bits
typedef __attribute__((ext_vector_type(16))) float f32x16;  // MFMA 32x32 acc

__device__ __forceinline__ float elu1(float x) {
    // elu(x) + 1  ==  x > 0 ? x + 1 : exp(x)
    return x > 0.f ? x + 1.f : __expf(x);
}

// fp32 -> bf16 bits, round-to-nearest-even
__device__ __forceinline__ short f2bf(float x) {
    unsigned u = __float_as_uint(x);
    return (short)((u + 0x7FFFu + ((u >> 16) & 1u)) >> 16);
}

#define LGKMCNT0() asm volatile("s_waitcnt lgkmcnt(0)" ::: "memory")
// raw barrier: does NOT drain vmcnt (unlike __syncthreads), so global loads
// issued before it stay in flight. lgkmcnt(0) first = LDS ops visible.
#define BAR() do { LGKMCNT0(); __builtin_amdgcn_s_barrier(); \
                   asm volatile("" ::: "memory"); } while (0)

// ---------------------------------------------------------------------------
// Phase 1 (R13): copy out_kernel's PROVEN staging shape (256-thr blocks,
// plain float4 loads, issue-all-then-sync — delivers ~26B/cyc/CU on this
// exact stride, 3x any previous p1), keep the proven AGPR-MFMA compute.
// Block = (nh, 256-row chunk); 4 iterations of 64 rows:
//   BAR(A) -> transform(elu*mask,ksum)+ds_write tile -> BAR(B)
//   -> issue next tile's 8 float4 loads (in flight across BAR(A))
//   -> wave wv MFMAs rows [16wv,16wv+16) from LDS.
// R12 falsified latency-depth; R7 showed reg-dbuf spills at cap<~170 --
// here __launch_bounds__(256,2) caps VGPR at 256: no spill.
// Tail: ksum LDS reduce + acc tree-combine (waves 2,3 -> waves 0,1 -> 0),
// single dump slot -> CH=16 so reduce reads only 17MB.
// Fragment mapping (verified R5-R12): A row d=l&31(+32td) k=8*(l>>5)+j;
// B col m=l&31(+32tm); C/D col=l&31, row=(r&3)+8*(r>>2)+4*(l>>5).
// ---------------------------------------------------------------------------
template<int ITERS>
__global__ __launch_bounds__(256, 2) void kv_partial_kernel(
    const float* __restrict__ keys, const float* __restrict__ values,
    const float* __restrict__ mask, float* __restrict__ pkv,
    float* __restrict__ pks)
{
    __shared__ float Kls[64][64];    // 16 KB tile; reused as combine buf
    __shared__ float Vls[64][64];    // 16 KB tile; reused as combine buf
    __shared__ float Mls[ITERS * 64];

    const int nh = blockIdx.x, n = nh >> 4, h = nh & 15;
    const int chunk = blockIdx.y;
    const int t = threadIdx.x, wv = t >> 6, l = t & 63;
    const int half = l >> 5, col = l & 31;
    const int r0 = t >> 4, c4 = (t & 15) * 4;   // staging role

    const int s0 = chunk * (ITERS * 64);
    const float* kb = keys   + ((size_t)(n * 4096 + s0) * 16 + h) * 64;
    const float* vb = values + ((size_t)(n * 4096 + s0) * 16 + h) * 64;

    if (t < ITERS * 16)
        *(float4*)&Mls[t * 4] = *(const float4*)(mask + n * 4096 + s0 + t * 4);

    f32x16 acc[2][2];
    #pragma unroll
    for (int a = 0; a < 2; ++a)
        #pragma unroll
        for (int b = 0; b < 2; ++b)
            #pragma unroll
            for (int r = 0; r < 16; ++r) acc[a][b][r] = 0.f;
    float4 ks4 = make_float4(0.f, 0.f, 0.f, 0.f);

    float4 kr[4], vr[4];
    #pragma unroll
    for (int k = 0; k < 4; ++k) {     // prologue: tile 0 (8 float4/thread)
        const size_t go = (size_t)(r0 + 16 * k) * 1024 + c4;
        kr[k] = *(const float4*)(kb + go);
        vr[k] = *(const float4*)(vb + go);
    }

    #pragma unroll
    for (int it = 0; it < ITERS; ++it) {
        BAR();   // (A) prior tile's LDS reads done; Mls visible at it==0
        #pragma unroll
        for (int k = 0; k < 4; ++k) {
            const float msk = Mls[it * 64 + r0 + 16 * k];
            float4 kk = kr[k];
            kk.x = elu1(kk.x) * msk; kk.y = elu1(kk.y) * msk;
            kk.z = elu1(kk.z) * msk; kk.w = elu1(kk.w) * msk;
            ks4.x += kk.x; ks4.y += kk.y; ks4.z += kk.z; ks4.w += kk.w;
            *(float4*)&Kls[r0 + 16 * k][c4] = kk;
            *(float4*)&Vls[r0 + 16 * k][c4] = vr[k];
        }
        BAR();   // (B) tile staged & visible
        if (it + 1 < ITERS) {          // issue next tile; stays in flight
            #pragma unroll
            for (int k = 0; k < 4; ++k) {
                const size_t go = (size_t)(r0 + 16 * k + 64 * (it + 1)) * 1024 + c4;
                kr[k] = *(const float4*)(kb + go);
                vr[k] = *(const float4*)(vb + go);
            }
        }
        // compute: wave's 16 rows; scalar LDS reads are 2-way-bank (free)
        short8 ka0, ka1, va0, va1;
        #pragma unroll
        for (int j = 0; j < 8; ++j) {
            const int s = 16 * wv + 8 * half + j;
            ka0[j] = f2bf(Kls[s][col]);
            ka1[j] = f2bf(Kls[s][col + 32]);
            va0[j] = f2bf(Vls[s][col]);
            va1[j] = f2bf(Vls[s][col + 32]);
        }
        acc[0][0] = __builtin_amdgcn_mfma_f32_32x32x16_bf16(ka0, va0, acc[0][0], 0, 0, 0);
        acc[0][1] = __builtin_amdgcn_mfma_f32_32x32x16_bf16(ka0, va1, acc[0][1], 0, 0, 0);
        acc[1][0] = __builtin_amdgcn_mfma_f32_32x32x16_bf16(ka1, va0, acc[1][0], 0, 0, 0);
        acc[1][1] = __builtin_amdgcn_mfma_f32_32x32x16_bf16(ka1, va1, acc[1][1], 0, 0, 0);
    }

    // ---- ksum block reduce (thread covers cols c4..c4+3 of its staged rows)
    BAR();
    *(float4*)&Kls[r0][c4] = ks4;            // Ksr[16][64] region
    BAR();
    if (t < 64) {
        float s = 0.f;
        #pragma unroll
        for (int r = 0; r < 16; ++r) s += Kls[r][t];
        pks[((size_t)chunk * 64 + nh) * 64 + t] = s;
    }
    BAR();

    // ---- acc tree-combine across waves (buffers = Kls, Vls; [idx][l] layout)
    float* cb0 = &Kls[0][0];
    float* cb1 = &Vls[0][0];
#define FLATW(BUF)                                                         \
    { _Pragma("unroll") for (int td = 0; td < 2; ++td)                     \
      _Pragma("unroll") for (int tm = 0; tm < 2; ++tm)                     \
      _Pragma("unroll") for (int r = 0; r < 16; ++r)                       \
          BUF[((td * 2 + tm) * 16 + r) * 64 + l] = acc[td][tm][r]; }
#define FLATR(BUF)                                                         \
    { _Pragma("unroll") for (int td = 0; td < 2; ++td)                     \
      _Pragma("unroll") for (int tm = 0; tm < 2; ++tm)                     \
      _Pragma("unroll") for (int r = 0; r < 16; ++r)                       \
          acc[td][tm][r] += BUF[((td * 2 + tm) * 16 + r) * 64 + l]; }
    if (wv == 2) FLATW(cb0);
    if (wv == 3) FLATW(cb1);
    BAR();
    if (wv == 0) FLATR(cb0);
    if (wv == 1) FLATR(cb1);
    BAR();
    if (wv == 1) FLATW(cb0);
    BAR();
    if (wv == 0) {
        FLATR(cb0);
        // dump combined partial in [d][m] order (verified C/D layout)
        float* pb = pkv + ((size_t)chunk * 64 + nh) * 4096;
        #pragma unroll
        for (int td = 0; td < 2; ++td)
            #pragma unroll
            for (int tm = 0; tm < 2; ++tm)
                #pragma unroll
                for (int r = 0; r < 16; ++r) {
                    const int d = 32 * td + (r & 3) + 8 * (r >> 2) + 4 * half;
                    pb[(size_t)d * 64 + 32 * tm + col] = acc[td][tm][r];
                }
    }
#undef FLATW
#undef FLATR
}

// ---------------------------------------------------------------------------
// Reduce: kvt[nh][d][m] = sum_c pkv[c][nh][d][m];  ksum[nh][d] = sum_c pks.
// ---------------------------------------------------------------------------
__global__ __launch_bounds__(256) void kv_reduce_kernel(
    const float* __restrict__ pkv, const float* __restrict__ pks,
    float* __restrict__ kvt, float* __restrict__ ksum, int CH)
{
    const int nh = blockIdx.x;
    const int f4 = blockIdx.y * 256 + threadIdx.x;   // float4 slot 0..1023
    float4 s4 = make_float4(0.f, 0.f, 0.f, 0.f);
    #pragma unroll 4
    for (int c = 0; c < CH; ++c) {
        const float4 v = *(const float4*)(pkv + ((size_t)c * 64 + nh) * 4096 + f4 * 4);
        s4.x += v.x; s4.y += v.y; s4.z += v.z; s4.w += v.w;
    }
    *(float4*)(kvt + (size_t)nh * 4096 + f4 * 4) = s4;

    if (blockIdx.y == 0 && threadIdx.x < 64) {
        float s = 0.f;
        #pragma unroll 4
        for (int c = 0; c < CH; ++c)
            s += pks[((size_t)c * 64 + nh) * 64 + threadIdx.x];
        ksum[nh * 64 + threadIdx.x] = s;
    }
}

// ---------------------------------------------------------------------------
// Phase 2: out[n,l,h,m] = z_l * sum_d Q'[l,d] * KVT[d,m],
//          z_l = 1/(sum_d Q'[l,d]*Ksum[d] + EPS)   (R8/R9 version, ~BW-bound)
// ---------------------------------------------------------------------------
__global__ __launch_bounds__(256) void out_kernel(
    const float* __restrict__ queries, const float* __restrict__ kvt,
    const float* __restrict__ ksum, float* __restrict__ out)
{
    __shared__ float Qs[64][68];    // [l][d]
    __shared__ float KVs[64][68];   // [d][m]
    __shared__ float Ksm[64];

    const int nh = blockIdx.x;
    const int n = nh >> 4, h = nh & 15;
    const int t = threadIdx.x;
    const int l0 = blockIdx.y * 64;

    #pragma unroll
    for (int k = 0; k < 4; ++k) {
        const int idx = t + k * 256;
        *(float4*)&KVs[idx >> 4][(idx & 15) * 4] =
            *(const float4*)(kvt + (size_t)nh * 4096 + idx * 4);
    }
    if (t < 64) Ksm[t] = ksum[nh * 64 + t];

    #pragma unroll
    for (int k = 0; k < 4; ++k) {
        const int idx = t + k * 256;
        const int row = idx >> 4, seg = idx & 15;
        const size_t g = ((size_t)(n * 4096 + l0 + row) * 16 + h) * 64 + seg * 4;
        float4 q4 = *(const float4*)(queries + g);
        q4.x = elu1(q4.x);
        q4.y = elu1(q4.y);
        q4.z = elu1(q4.z);
        q4.w = elu1(q4.w);
        *(float4*)&Qs[row][seg * 4] = q4;
    }
    __syncthreads();

    const int mg = t & 7;          // m cols 4mg..+3 and 32+4mg..+3
    const int lg = t >> 3;         // 0..31; rows lg, lg+32

    float acc[2][8];
    float zacc[2] = {0.f, 0.f};
    #pragma unroll
    for (int i = 0; i < 2; ++i)
        #pragma unroll
        for (int j = 0; j < 8; ++j) acc[i][j] = 0.f;

    #pragma unroll 4
    for (int d0 = 0; d0 < 64; d0 += 4) {
        const float4 km4 = *(const float4*)&Ksm[d0];
        float4 q[2];
        q[0] = *(const float4*)&Qs[lg][d0];
        q[1] = *(const float4*)&Qs[lg + 32][d0];
        #pragma unroll
        for (int i = 0; i < 2; ++i)
            zacc[i] += q[i].x * km4.x + q[i].y * km4.y +
                       q[i].z * km4.z + q[i].w * km4.w;
        #pragma unroll
        for (int r = 0; r < 4; ++r) {
            const float4 kva = *(const float4*)&KVs[d0 + r][mg * 4];
            const float4 kvb = *(const float4*)&KVs[d0 + r][32 + mg * 4];
            #pragma unroll
            for (int i = 0; i < 2; ++i) {
                const float qc = ((const float*)&q[i])[r];
                acc[i][0] = fmaf(qc, kva.x, acc[i][0]);
                acc[i][1] = fmaf(qc, kva.y, acc[i][1]);
                acc[i][2] = fmaf(qc, kva.z, acc[i][2]);
                acc[i][3] = fmaf(qc, kva.w, acc[i][3]);
                acc[i][4] = fmaf(qc, kvb.x, acc[i][4]);
                acc[i][5] = fmaf(qc, kvb.y, acc[i][5]);
                acc[i][6] = fmaf(qc, kvb.z, acc[i][6]);
                acc[i][7] = fmaf(qc, kvb.w, acc[i][7]);
            }
        }
    }

    #pragma unroll
    for (int i = 0; i < 2; ++i) {
        const float z = 1.f / (zacc[i] + EPS);
        const int row = l0 + lg + 32 * i;
        const size_t g = ((size_t)(n * 4096 + row) * 16 + h) * 64;
        float4 o;
        o.x = acc[i][0] * z; o.y = acc[i][1] * z;
        o.z = acc[i][2] * z; o.w = acc[i][3] * z;
        *(float4*)(out + g + mg * 4) = o;
        o.x = acc[i][4] * z; o.y = acc[i][5] * z;
        o.z = acc[i][6] * z; o.w = acc[i][7] * z;
        *(float4*)(out + g + 32 + mg * 4) = o;
    }
}

extern "C" void kernel_launch(void* const* d_in, const int* in_sizes, int n_in,
                              void* d_out, int out_size, void* d_ws, size_t ws_size,
                              hipStream_t stream) {
    const float* queries = (const float*)d_in[0];
    const float* keys    = (const float*)d_in[1];
    const float* values  = (const float*)d_in[2];
    const float* mask    = (const float*)d_in[3];
    float* out = (float*)d_out;

    auto need = [](int CH) {
        return ((size_t)CH * 64 * 4096 + (size_t)CH * 64 * 64 +
                (size_t)64 * 4096 + 64 * 64) * sizeof(float);
    };
    // CH=16 (18MB, proven fits in R1); fallback CH=8.
    const int CH = (need(16) <= ws_size) ? 16 : 8;

    float* pkv  = (float*)d_ws;                         // [CH][64][64][64] (d,m)
    float* pks  = pkv + (size_t)CH * 64 * 4096;         // [CH][64][64]
    float* kvt  = pks + (size_t)CH * 64 * 64;           // [64][64][64] (d,m)
    float* ksum = kvt + (size_t)64 * 4096;              // [64][64]

    if (CH == 16)
        kv_partial_kernel<4><<<dim3(64, 16), 256, 0, stream>>>(keys, values, mask, pkv, pks);
    else
        kv_partial_kernel<8><<<dim3(64, 8), 256, 0, stream>>>(keys, values, mask, pkv, pks);
    kv_reduce_kernel<<<dim3(64, 4), 256, 0, stream>>>(pkv, pks, kvt, ksum, CH);
    out_kernel<<<dim3(64, 64), 256, 0, stream>>>(queries, kvt, ksum, out);
}